// Round 1
// baseline (1390.602 us; speedup 1.0000x reference)
//
#include <hip/hip_runtime.h>
#include <math.h>

// Problem constants (from reference)
#define B_      8
#define S_      4096
#define H_      2048
#define HINT_   4
#define WS_     16
#define STRIDE_ 8
#define MLPH_   64
#define NW_     512            // windows per batch (stride 8 over 4096, all full-ish)
#define WPB_    8              // windows per block
#define ROWS_   72             // rows spanned per block: 8*WPB_ + 8
#define KT_     68             // k-tiles of 32 covering K=2052 padded to 2176
#define KPAD_   2176
#define LDK_    2184           // row stride in shorts: 2176 + 8 -> bank offset 4 (conflict-free-ish)
#define NT_     4              // n-tiles of 16 covering MLPH_=64

typedef float  floatx4 __attribute__((ext_vector_type(4)));
typedef short  shortx8 __attribute__((ext_vector_type(8)));

__device__ __forceinline__ unsigned short f2b(float x) {
    // float -> bf16, round-to-nearest-even (inputs are finite normals)
    unsigned u = __float_as_uint(x);
    u += 0x7FFFu + ((u >> 16) & 1u);
    return (unsigned short)(u >> 16);
}

// Repack W1 (2052 x 64, row-major fp32) into bf16 MFMA B-fragment order:
// for n-tile nt, k-tile kt, lane L, j in 0..7:  B[k = kt*32 + (L>>4)*8 + j][n = nt*16 + (L&15)]
// flat index: (((nt*KT_ + kt)*64 + L)*8 + j). Zero-pad k >= 2052.
__global__ void prep_w1(const float* __restrict__ W1, unsigned short* __restrict__ W1B) {
    const int blk  = blockIdx.x;            // 0 .. NT_*KT_-1 = 271
    const int nt   = blk / KT_;
    const int kt   = blk % KT_;
    const int lane = threadIdx.x;           // 64 threads
    const int n     = nt * 16 + (lane & 15);
    const int kbase = kt * 32 + (lane >> 4) * 8;
    unsigned short tmp[8];
#pragma unroll
    for (int j = 0; j < 8; ++j) {
        const int k = kbase + j;
        const float v = (k < (H_ + HINT_)) ? W1[(size_t)k * MLPH_ + n] : 0.0f;
        tmp[j] = f2b(v);
    }
    *(uint4*)(W1B + (((size_t)nt * KT_ + kt) * 64 + lane) * 8) = *(const uint4*)tmp;
}

__global__ __launch_bounds__(512, 4) void wbh_kernel(
    const float* __restrict__ hidden,   // (B,S,H) fp32
    const int*   __restrict__ amask,    // (B,S) int32
    const float* __restrict__ hintf,    // (B,S,HINT) fp32
    const float* __restrict__ b1,       // (64)
    const float* __restrict__ W2,       // (64)
    const float* __restrict__ b2,       // (1)
    const unsigned short* __restrict__ W1B, // packed bf16 W1 fragments
    float* __restrict__ out)            // [0:4096) logits, [4096:8192) mask
{
    // LDS: pooled tile is M=16 rows (8 real windows + 8 zero rows) x LDK_ bf16
    __shared__ unsigned short pooledLds[16 * LDK_];   // 69,888 B
    __shared__ float amLds[ROWS_];
    __shared__ float hintLds[ROWS_ * HINT_];
    __shared__ float rinvLds[WPB_];
    __shared__ float partLds[WPB_ * 68];

    const int tid   = threadIdx.x;
    const int bid   = blockIdx.x;       // 512 blocks
    const int b     = bid >> 6;         // 64 chunks per batch
    const int chunk = bid & 63;
    const int w0    = chunk * WPB_;
    const int s0    = chunk * (WPB_ * STRIDE_);   // first row of this block

    // ---- Phase 0: zero pooled LDS; stage mask + hint rows ----
    {
        unsigned int* p = (unsigned int*)pooledLds;
        const int n4 = 16 * LDK_ / 2;
        for (int i = tid; i < n4; i += 512) p[i] = 0u;
    }
    if (tid < ROWS_) {
        const int p = s0 + tid;
        amLds[tid] = (p < S_) ? (float)amask[b * S_ + p] : 0.0f;
    }
    if (tid < ROWS_ * HINT_) {
        const int rr = tid >> 2;                  // HINT_ == 4
        const int p  = s0 + rr;
        hintLds[tid] = (p < S_) ? hintf[((size_t)b * S_ + p) * HINT_ + (tid & 3)] : 0.0f;
    }
    __syncthreads();

    // ---- Phase 1a: per-window mask sums -> 1/denom, write window_mask output ----
    if (tid < WPB_) {
        float s = 0.f;
#pragma unroll
        for (int k = 0; k < WS_; ++k) s += amLds[tid * STRIDE_ + k];
        rinvLds[tid] = 1.0f / fmaxf(s, 1.0f);
        out[(size_t)(B_ * NW_) + (size_t)b * NW_ + w0 + tid] = (s > 0.f) ? 1.0f : 0.0f;
    }

    // ---- Phase 1b: masked pooling; 4 columns/thread, wave-uniform skip of mask==0 rows ----
    const int c0 = tid * 4;
    floatx4 acc[WPB_];
#pragma unroll
    for (int w = 0; w < WPB_; ++w) acc[w] = (floatx4){0.f, 0.f, 0.f, 0.f};

    const float* rowBase = hidden + ((size_t)b * S_ + s0) * H_ + c0;
#pragma unroll
    for (int g = 0; g < WPB_ + 1; ++g) {          // 9 groups of 8 rows = 72 rows
#pragma unroll
        for (int k = 0; k < STRIDE_; ++k) {
            const int rr = g * STRIDE_ + k;
            const float amv = amLds[rr];          // wave-uniform broadcast
            if (amv != 0.0f) {                    // mask values are exactly 0/1 -> add
                const floatx4 v = *(const floatx4*)(rowBase + (size_t)rr * H_);
                if (g < WPB_) acc[g]     += v;    // row in high window g
                if (g > 0)    acc[g - 1] += v;    // row in low window g-1
            }
        }
    }
    __syncthreads();   // rinvLds ready; everyone done with amLds broadcast reads

    // ---- Phase 1c: normalize + bf16 -> LDS (MFMA A-layout: pooled[w][c]) ----
#pragma unroll
    for (int w = 0; w < WPB_; ++w) {
        const float r = rinvLds[w];
        unsigned short q[4];
        q[0] = f2b(acc[w].x * r); q[1] = f2b(acc[w].y * r);
        q[2] = f2b(acc[w].z * r); q[3] = f2b(acc[w].w * r);
        *(uint2*)(&pooledLds[w * LDK_ + c0]) = *(const uint2*)q;
    }
    if (tid < WPB_ * HINT_) {                     // hint pooling: 32 threads
        const int w = tid >> 2, hc = tid & 3;
        float s = 0.f;
#pragma unroll
        for (int k = 0; k < WS_; ++k) {
            const int rr = w * STRIDE_ + k;
            s += amLds[rr] * hintLds[rr * HINT_ + hc];
        }
        pooledLds[w * LDK_ + H_ + hc] = f2b(s * rinvLds[w]);
    }
    __syncthreads();

    // ---- Phase 2: MFMA (16x2176)@(2176x64) -> pre-activation; waves 0..3 = n-tiles ----
    const int wid  = tid >> 6;
    const int lane = tid & 63;
    if (wid < NT_) {
        floatx4 dacc = (floatx4){0.f, 0.f, 0.f, 0.f};
        // A-frag: lane holds A[m=lane&15][k = kt*32 + (lane>>4)*8 + j]
        const unsigned short* aBase = pooledLds + (lane & 15) * LDK_ + (lane >> 4) * 8;
        const unsigned short* bBase = W1B + (((size_t)wid * KT_) * 64 + lane) * 8;
#pragma unroll 4
        for (int kt = 0; kt < KT_; ++kt) {
            const shortx8 af = *(const shortx8*)(aBase + kt * 32);
            const shortx8 bf = *(const shortx8*)(bBase + (size_t)kt * 64 * 8);
            dacc = __builtin_amdgcn_mfma_f32_16x16x32_bf16(af, bf, dacc, 0, 0, 0);
        }
        // D: lane reg r holds D[row=(lane>>4)*4+r][col=lane&15]; row = window, col -> j
        const int j   = wid * 16 + (lane & 15);
        const float b1v = b1[j];
        const float w2v = W2[j];
        const int m0  = (lane >> 4) * 4;
        if (m0 < WPB_) {                          // rows 8..15 are the zero pad
#pragma unroll
            for (int r = 0; r < 4; ++r) {
                const float a  = dacc[r] + b1v;
                const float gv = 0.5f * a * (1.0f + erff(a * 0.70710678118654752f)); // exact gelu
                partLds[(m0 + r) * 68 + j] = gv * w2v;
            }
        }
    }
    __syncthreads();

    // ---- Phase 3: reduce 64 j-partials per window -> logit ----
    if (tid < WPB_) {
        float s = b2[0];
#pragma unroll
        for (int j = 0; j < MLPH_; ++j) s += partLds[tid * 68 + j];
        out[(size_t)b * NW_ + w0 + tid] = s;
    }
}

extern "C" void kernel_launch(void* const* d_in, const int* in_sizes, int n_in,
                              void* d_out, int out_size, void* d_ws, size_t ws_size,
                              hipStream_t stream) {
    const float* hidden = (const float*)d_in[0];
    const int*   amask  = (const int*)d_in[1];
    const float* hintf  = (const float*)d_in[2];
    const float* W1     = (const float*)d_in[3];
    const float* b1     = (const float*)d_in[4];
    const float* W2     = (const float*)d_in[5];
    const float* b2     = (const float*)d_in[6];
    float* out          = (float*)d_out;

    unsigned short* W1B = (unsigned short*)d_ws;   // needs NT_*KT_*64*8*2 = 278,528 B

    // d_ws is re-poisoned before every timed launch -> rebuild the packed W1 every call
    prep_w1<<<NT_ * KT_, 64, 0, stream>>>(W1, W1B);
    wbh_kernel<<<B_ * (NW_ / WPB_), 512, 0, stream>>>(
        hidden, amask, hintf, b1, W2, b2, W1B, out);
}

// Round 2
// 349.218 us; speedup vs baseline: 3.9820x; 3.9820x over previous
//
#include <hip/hip_runtime.h>
#include <math.h>

// Problem constants (from reference)
#define B_      8
#define S_      4096
#define H_      2048
#define HINT_   4
#define WS_     16
#define STRIDE_ 8
#define MLPH_   64
#define NW_     512            // windows per batch
#define WPB_    8              // windows per block
#define ROWS_   72             // rows spanned per block: 8*WPB_ + 8
#define KT_     68             // k-tiles of 32 covering K=2052 padded to 2176
#define KPAD_   2176
#define LDK_    2184           // LDS row stride in shorts (pad 8 -> bank offset 4)
#define NT_     4              // n-tiles of 16 covering MLPH_=64

typedef float  floatx4 __attribute__((ext_vector_type(4)));
typedef short  shortx8 __attribute__((ext_vector_type(8)));

__device__ __forceinline__ unsigned short f2b(float x) {
    // float -> bf16, round-to-nearest-even (inputs are finite normals)
    unsigned u = __float_as_uint(x);
    u += 0x7FFFu + ((u >> 16) & 1u);
    return (unsigned short)(u >> 16);
}

// Repack W1 (2052 x 64, row-major fp32) into bf16 MFMA B-fragment order:
// nt, kt, lane L, j:  B[k = kt*32 + (L>>4)*8 + j][n = nt*16 + (L&15)]
// flat: (((nt*KT_ + kt)*64 + L)*8 + j). Zero-pad k >= 2052.
__global__ void prep_w1(const float* __restrict__ W1, unsigned short* __restrict__ W1B) {
    const int blk  = blockIdx.x;            // 0 .. NT_*KT_-1
    const int nt   = blk / KT_;
    const int kt   = blk % KT_;
    const int lane = threadIdx.x;           // 64 threads
    const int n     = nt * 16 + (lane & 15);
    const int kbase = kt * 32 + (lane >> 4) * 8;
    unsigned short tmp[8];
#pragma unroll
    for (int j = 0; j < 8; ++j) {
        const int k = kbase + j;
        const float v = (k < (H_ + HINT_)) ? W1[(size_t)k * MLPH_ + n] : 0.0f;
        tmp[j] = f2b(v);
    }
    *(uint4*)(W1B + (((size_t)nt * KT_ + kt) * 64 + lane) * 8) = *(const uint4*)tmp;
}

__global__ __launch_bounds__(512) void wbh_kernel(
    const float* __restrict__ hidden,   // (B,S,H) fp32
    const int*   __restrict__ amask,    // (B,S) int32
    const float* __restrict__ hintf,    // (B,S,HINT) fp32
    const float* __restrict__ b1,       // (64)
    const float* __restrict__ W2,       // (64)
    const float* __restrict__ b2,       // (1)
    const unsigned short* __restrict__ W1B, // packed bf16 W1 fragments
    float* __restrict__ out)            // [0:4096) logits, [4096:8192) mask
{
    __shared__ unsigned short pooledLds[16 * LDK_];   // 69,888 B; M=16 (8 real + 8 pad rows)
    __shared__ float amLds[ROWS_];
    __shared__ float hintLds[ROWS_ * HINT_];
    __shared__ float rinvLds[WPB_];
    __shared__ float partLds[WPB_ * 68];

    const int tid   = threadIdx.x;
    const int bid   = blockIdx.x;       // 512 blocks
    const int b     = bid >> 6;
    const int chunk = bid & 63;
    const int w0    = chunk * WPB_;
    const int s0    = chunk * (WPB_ * STRIDE_);

    // ---- Phase 0: zero pooled LDS; stage mask + hint rows ----
    {
        unsigned int* p = (unsigned int*)pooledLds;
        const int n4 = 16 * LDK_ / 2;
        for (int i = tid; i < n4; i += 512) p[i] = 0u;
    }
    if (tid < ROWS_) {
        const int p = s0 + tid;
        amLds[tid] = (p < S_) ? (float)amask[b * S_ + p] : 0.0f;
    }
    if (tid < ROWS_ * HINT_) {
        const int rr = tid >> 2;                  // HINT_ == 4
        const int p  = s0 + rr;
        hintLds[tid] = (p < S_) ? hintf[((size_t)b * S_ + p) * HINT_ + (tid & 3)] : 0.0f;
    }
    __syncthreads();

    // ---- Phase 1a: per-window mask sums -> 1/denom, write window_mask output ----
    if (tid < WPB_) {
        float s = 0.f;
#pragma unroll
        for (int k = 0; k < WS_; ++k) s += amLds[tid * STRIDE_ + k];
        rinvLds[tid] = 1.0f / fmaxf(s, 1.0f);
        out[(size_t)(B_ * NW_) + (size_t)b * NW_ + w0 + tid] = (s > 0.f) ? 1.0f : 0.0f;
    }
    __syncthreads();   // rinvLds ready before fused finalize below

    // ---- Phase 1b: masked pooling, rolling 2-group window (NO accumulator array) ----
    // Window w = group w (rows w*8..w*8+7) + group w+1 (rows w*8+8..w*8+15).
    // Keep only cur/prev group sums in registers; finalize window g-1 when group g done.
    const int c0 = tid * 4;
    const float* rowBase = hidden + ((size_t)b * S_ + s0) * H_ + c0;

    floatx4 prev = (floatx4){0.f, 0.f, 0.f, 0.f};
#pragma unroll
    for (int g = 0; g <= WPB_; ++g) {
        floatx4 cur = (floatx4){0.f, 0.f, 0.f, 0.f};
#pragma unroll
        for (int k = 0; k < STRIDE_; ++k) {
            const int rr = g * STRIDE_ + k;
            const float amv = amLds[rr];          // LDS broadcast, block-uniform
            if (amv != 0.0f) {                    // mask is 0/1 -> plain add
                cur += *(const floatx4*)(rowBase + (size_t)rr * H_);
            }
        }
        if (g >= 1) {                             // finalize window w = g-1
            const int w = g - 1;
            const floatx4 s = prev + cur;
            const float r = rinvLds[w];
            unsigned short q[4];
            q[0] = f2b(s.x * r); q[1] = f2b(s.y * r);
            q[2] = f2b(s.z * r); q[3] = f2b(s.w * r);
            *(uint2*)(&pooledLds[w * LDK_ + c0]) = *(const uint2*)q;
        }
        prev = cur;
    }

    if (tid < WPB_ * HINT_) {                     // hint pooling: 32 threads
        const int w = tid >> 2, hc = tid & 3;
        float s = 0.f;
#pragma unroll
        for (int k = 0; k < WS_; ++k) {
            const int rr = w * STRIDE_ + k;
            s += amLds[rr] * hintLds[rr * HINT_ + hc];
        }
        pooledLds[w * LDK_ + H_ + hc] = f2b(s * rinvLds[w]);
    }
    __syncthreads();

    // ---- Phase 2: MFMA (16x2176)@(2176x64); waves 0..3 = n-tiles of 16 ----
    const int wid  = tid >> 6;
    const int lane = tid & 63;
    if (wid < NT_) {
        floatx4 dacc = (floatx4){0.f, 0.f, 0.f, 0.f};
        // A-frag: lane holds A[m=lane&15][k = kt*32 + (lane>>4)*8 + j]
        const unsigned short* aBase = pooledLds + (lane & 15) * LDK_ + (lane >> 4) * 8;
        const unsigned short* bBase = W1B + (((size_t)wid * KT_) * 64 + lane) * 8;
#pragma unroll 4
        for (int kt = 0; kt < KT_; ++kt) {
            const shortx8 af = *(const shortx8*)(aBase + kt * 32);
            const shortx8 bf = *(const shortx8*)(bBase + (size_t)kt * 64 * 8);
            dacc = __builtin_amdgcn_mfma_f32_16x16x32_bf16(af, bf, dacc, 0, 0, 0);
        }
        // D: lane reg r holds D[row=(lane>>4)*4+r][col=lane&15]
        const int j   = wid * 16 + (lane & 15);
        const float b1v = b1[j];
        const float w2v = W2[j];
        const int m0  = (lane >> 4) * 4;
        if (m0 < WPB_) {                          // rows 8..15 are zero pad
#pragma unroll
            for (int r = 0; r < 4; ++r) {
                const float a  = dacc[r] + b1v;
                const float gv = 0.5f * a * (1.0f + erff(a * 0.70710678118654752f)); // exact gelu
                partLds[(m0 + r) * 68 + j] = gv * w2v;
            }
        }
    }
    __syncthreads();

    // ---- Phase 3: reduce 64 j-partials per window -> logit ----
    if (tid < WPB_) {
        float s = b2[0];
#pragma unroll
        for (int j = 0; j < MLPH_; ++j) s += partLds[tid * 68 + j];
        out[(size_t)b * NW_ + w0 + tid] = s;
    }
}

extern "C" void kernel_launch(void* const* d_in, const int* in_sizes, int n_in,
                              void* d_out, int out_size, void* d_ws, size_t ws_size,
                              hipStream_t stream) {
    const float* hidden = (const float*)d_in[0];
    const int*   amask  = (const int*)d_in[1];
    const float* hintf  = (const float*)d_in[2];
    const float* W1     = (const float*)d_in[3];
    const float* b1     = (const float*)d_in[4];
    const float* W2     = (const float*)d_in[5];
    const float* b2     = (const float*)d_in[6];
    float* out          = (float*)d_out;

    unsigned short* W1B = (unsigned short*)d_ws;   // NT_*KT_*64*8*2 = 278,528 B

    // d_ws is re-poisoned before every timed launch -> rebuild packed W1 every call
    prep_w1<<<NT_ * KT_, 64, 0, stream>>>(W1, W1B);
    wbh_kernel<<<B_ * (NW_ / WPB_), 512, 0, stream>>>(
        hidden, amask, hintf, b1, W2, b2, W1B, out);
}

// Round 3
// 349.164 us; speedup vs baseline: 3.9827x; 1.0002x over previous
//
#include <hip/hip_runtime.h>
#include <math.h>

// Problem constants (from reference)
#define B_      8
#define S_      4096
#define H_      2048
#define HINT_   4
#define WS_     16
#define STRIDE_ 8
#define MLPH_   64
#define NW_     512            // windows per batch
#define WPB_    8              // windows per block
#define ROWS_   72             // rows spanned per block: 8*WPB_ + 8
#define KT_     68             // k-tiles of 32 covering K=2052 padded to 2176
#define KPAD_   2176
#define LDK_    2184           // LDS row stride in shorts (pad 8)
#define NT_     4              // n-tiles of 16 covering MLPH_=64
#define PLD_    66             // partLds row stride (floats); 66 avoids 32-multiple strides

typedef float  floatx4 __attribute__((ext_vector_type(4)));
typedef short  shortx8 __attribute__((ext_vector_type(8)));

__device__ __forceinline__ unsigned short f2b(float x) {
    // float -> bf16, round-to-nearest-even (inputs are finite normals)
    unsigned u = __float_as_uint(x);
    u += 0x7FFFu + ((u >> 16) & 1u);
    return (unsigned short)(u >> 16);
}

// Repack W1 (2052 x 64, row-major fp32) into bf16 MFMA B-fragment order:
// nt, kt, lane L, j:  B[k = kt*32 + (L>>4)*8 + j][n = nt*16 + (L&15)]
// flat: (((nt*KT_ + kt)*64 + L)*8 + j). Zero-pad k >= 2052.
__global__ void prep_w1(const float* __restrict__ W1, unsigned short* __restrict__ W1B) {
    const int blk  = blockIdx.x;            // 0 .. NT_*KT_-1
    const int nt   = blk / KT_;
    const int kt   = blk % KT_;
    const int lane = threadIdx.x;           // 64 threads
    const int n     = nt * 16 + (lane & 15);
    const int kbase = kt * 32 + (lane >> 4) * 8;
    unsigned short tmp[8];
#pragma unroll
    for (int j = 0; j < 8; ++j) {
        const int k = kbase + j;
        const float v = (k < (H_ + HINT_)) ? W1[(size_t)k * MLPH_ + n] : 0.0f;
        tmp[j] = f2b(v);
    }
    *(uint4*)(W1B + (((size_t)nt * KT_ + kt) * 64 + lane) * 8) = *(const uint4*)tmp;
}

__global__ __launch_bounds__(512, 8) void wbh_kernel(
    const float* __restrict__ hidden,   // (B,S,H) fp32
    const int*   __restrict__ amask,    // (B,S) int32
    const float* __restrict__ hintf,    // (B,S,HINT) fp32
    const float* __restrict__ b1,       // (64)
    const float* __restrict__ W2,       // (64)
    const float* __restrict__ b2,       // (1)
    const unsigned short* __restrict__ W1B, // packed bf16 W1 fragments
    float* __restrict__ out)            // [0:4096) logits, [4096:8192) mask
{
    // Only the 8 REAL window rows are stored. MFMA D rows 8-15 depend only on
    // A rows 8-15; lanes with m>=8 alias row m&7, producing duplicate D rows
    // we never read. LDS: 34,944 B instead of 69,888 -> 4 blocks/CU.
    __shared__ unsigned short pooledLds[WPB_ * LDK_];
    __shared__ float amLds[ROWS_];
    __shared__ float hintLds[ROWS_ * HINT_];
    __shared__ float rinvLds[WPB_];
    __shared__ unsigned amBitsLds[WPB_ + 1];       // per-8-row-group mask bits
    __shared__ float partLds[WPB_ * 2 * PLD_];     // raw MFMA partials (m,khalf)

    const int tid = threadIdx.x;
    const int bid = blockIdx.x;                    // 512 blocks
    // XCD-locality swizzle: 64 consecutive chunks per XCD (halo rows shared in L2)
    const int gid   = (bid & 7) * 64 + (bid >> 3);
    const int b     = gid >> 6;
    const int chunk = gid & 63;
    const int w0    = chunk * WPB_;
    const int s0    = chunk * (WPB_ * STRIDE_);

    // ---- Phase 0: zero only the k-pad cols (2052..2175) of the 8 rows; stage mask+hints ----
    if (tid < 8 * 62) {                            // 62 uints x 8 rows
        const int row = tid / 62, cc = tid % 62;
        *(unsigned*)&pooledLds[row * LDK_ + 2052 + cc * 2] = 0u;
    }
    if (tid < ROWS_) {
        const int p = s0 + tid;
        amLds[tid] = (p < S_) ? (float)amask[b * S_ + p] : 0.0f;
    }
    if (tid < ROWS_ * HINT_) {
        const int rr = tid >> 2;                   // HINT_ == 4
        const int p  = s0 + rr;
        hintLds[tid] = (p < S_) ? hintf[((size_t)b * S_ + p) * HINT_ + (tid & 3)] : 0.0f;
    }
    __syncthreads();

    // ---- Phase 1a: denoms + window_mask output + per-group mask bits ----
    if (tid < WPB_) {
        float s = 0.f;
#pragma unroll
        for (int k = 0; k < WS_; ++k) s += amLds[tid * STRIDE_ + k];
        rinvLds[tid] = 1.0f / fmaxf(s, 1.0f);
        out[(size_t)(B_ * NW_) + (size_t)b * NW_ + w0 + tid] = (s > 0.f) ? 1.0f : 0.0f;
    }
    if (tid < WPB_ + 1) {
        unsigned bits = 0;
#pragma unroll
        for (int k = 0; k < STRIDE_; ++k)
            bits |= (amLds[tid * STRIDE_ + k] != 0.0f ? 1u : 0u) << k;
        amBitsLds[tid] = bits;
    }
    __syncthreads();

    // ---- Phase 1b: masked pooling, rolling 2-group window; scalar-branch loads ----
    const int c0 = tid * 4;
    const float* rowBase = hidden + ((size_t)b * S_ + s0) * H_ + c0;

    floatx4 prev = (floatx4){0.f, 0.f, 0.f, 0.f};
#pragma unroll
    for (int g = 0; g <= WPB_; ++g) {
        const unsigned bits =
            (unsigned)__builtin_amdgcn_readfirstlane((int)amBitsLds[g]);
        floatx4 cur = (floatx4){0.f, 0.f, 0.f, 0.f};
#pragma unroll
        for (int k = 0; k < STRIDE_; ++k) {
            if (bits & (1u << k)) {                // wave-uniform scalar branch
                cur += *(const floatx4*)(rowBase + (size_t)(g * STRIDE_ + k) * H_);
            }
        }
        if (g >= 1) {                              // finalize window w = g-1
            const int w = g - 1;
            const floatx4 s = prev + cur;
            const float r = rinvLds[w];
            unsigned short q[4];
            q[0] = f2b(s.x * r); q[1] = f2b(s.y * r);
            q[2] = f2b(s.z * r); q[3] = f2b(s.w * r);
            *(uint2*)(&pooledLds[w * LDK_ + c0]) = *(const uint2*)q;
        }
        prev = cur;
    }

    if (tid < WPB_ * HINT_) {                      // hint pooling: 32 threads
        const int w = tid >> 2, hc = tid & 3;
        float s = 0.f;
#pragma unroll
        for (int k = 0; k < WS_; ++k) {
            const int rr = w * STRIDE_ + k;
            s += amLds[rr] * hintLds[rr * HINT_ + hc];
        }
        pooledLds[w * LDK_ + H_ + hc] = f2b(s * rinvLds[w]);
    }
    __syncthreads();

    // ---- Phase 2: MFMA (16x2176)@(2176x64) split over 8 waves: (n-tile, k-half) ----
    const int wid  = tid >> 6;
    const int lane = tid & 63;
    const int nt   = wid & 3;                      // n-tile of 16
    const int kh   = wid >> 2;                     // k-half: 34 k-tiles each
    {
        floatx4 dacc = (floatx4){0.f, 0.f, 0.f, 0.f};
        // A-frag: lane holds A[m=lane&15][k=kt*32+(lane>>4)*8+j]; row aliased m&7
        const unsigned short* aBase =
            pooledLds + (lane & 7) * LDK_ + (lane >> 4) * 8 + kh * 34 * 32;
        const unsigned short* bBase =
            W1B + (((size_t)nt * KT_ + kh * 34) * 64 + lane) * 8;
#pragma unroll 4
        for (int kt = 0; kt < 34; ++kt) {
            const shortx8 af = *(const shortx8*)(aBase + kt * 32);
            const shortx8 bf = *(const shortx8*)(bBase + (size_t)kt * 64 * 8);
            dacc = __builtin_amdgcn_mfma_f32_16x16x32_bf16(af, bf, dacc, 0, 0, 0);
        }
        // D: lane reg r holds D[row=(lane>>4)*4+r][col=lane&15]; rows >=8 are dups
        if (lane < 32) {
            const int m0 = (lane >> 4) * 4;
            const int j  = nt * 16 + (lane & 15);
#pragma unroll
            for (int r = 0; r < 4; ++r)
                partLds[((m0 + r) * 2 + kh) * PLD_ + j] = dacc[r];
        }
    }
    __syncthreads();

    // ---- Phase 3: wave w = window w; lane j; gelu + W2 + wave shuffle reduce ----
    {
        const int m = tid >> 6;                    // window within block
        const int j = tid & 63;
        const float a = partLds[(m * 2) * PLD_ + j] + partLds[(m * 2 + 1) * PLD_ + j]
                      + b1[j];
        float g = 0.5f * a * (1.0f + erff(a * 0.70710678118654752f)) * W2[j];
#pragma unroll
        for (int off = 32; off > 0; off >>= 1) g += __shfl_down(g, off, 64);
        if (j == 0) out[(size_t)b * NW_ + w0 + m] = g + b2[0];
    }
}

extern "C" void kernel_launch(void* const* d_in, const int* in_sizes, int n_in,
                              void* d_out, int out_size, void* d_ws, size_t ws_size,
                              hipStream_t stream) {
    const float* hidden = (const float*)d_in[0];
    const int*   amask  = (const int*)d_in[1];
    const float* hintf  = (const float*)d_in[2];
    const float* W1     = (const float*)d_in[3];
    const float* b1     = (const float*)d_in[4];
    const float* W2     = (const float*)d_in[5];
    const float* b2     = (const float*)d_in[6];
    float* out          = (float*)d_out;

    unsigned short* W1B = (unsigned short*)d_ws;   // NT_*KT_*64*8*2 = 278,528 B

    // d_ws is re-poisoned before every timed launch -> rebuild packed W1 every call
    prep_w1<<<NT_ * KT_, 64, 0, stream>>>(W1, W1B);
    wbh_kernel<<<B_ * (NW_ / WPB_), 512, 0, stream>>>(
        hidden, amask, hintf, b1, W2, b2, W1B, out);
}

// Round 4
// 349.156 us; speedup vs baseline: 3.9828x; 1.0000x over previous
//
#include <hip/hip_runtime.h>
#include <math.h>

// Problem constants (from reference)
#define B_      8
#define S_      4096
#define H_      2048
#define HINT_   4
#define WS_     16
#define STRIDE_ 8
#define MLPH_   64
#define NW_     512            // windows per batch
#define WPB_    8              // windows per block
#define ROWS_   72             // rows spanned per block: 8*WPB_ + 8
#define KT_     68             // k-tiles of 32 covering K=2052 padded to 2176
#define KPAD_   2176
#define LDK_    2184           // LDS row stride in shorts (pad 8)
#define NT_     4              // n-tiles of 16 covering MLPH_=64
#define PLD_    66             // partLds row stride (floats)

typedef float  floatx4 __attribute__((ext_vector_type(4)));
typedef short  shortx8 __attribute__((ext_vector_type(8)));

__device__ __forceinline__ unsigned short f2b(float x) {
    // float -> bf16, round-to-nearest-even (inputs are finite normals)
    unsigned u = __float_as_uint(x);
    u += 0x7FFFu + ((u >> 16) & 1u);
    return (unsigned short)(u >> 16);
}

// Repack W1 (2052 x 64, row-major fp32) into bf16 MFMA B-fragment order:
// nt, kt, lane L, j:  B[k = kt*32 + (L>>4)*8 + j][n = nt*16 + (L&15)]
// flat: (((nt*KT_ + kt)*64 + L)*8 + j). Zero-pad k >= 2052.
__global__ void prep_w1(const float* __restrict__ W1, unsigned short* __restrict__ W1B) {
    const int blk  = blockIdx.x;            // 0 .. NT_*KT_-1
    const int nt   = blk / KT_;
    const int kt   = blk % KT_;
    const int lane = threadIdx.x;           // 64 threads
    const int n     = nt * 16 + (lane & 15);
    const int kbase = kt * 32 + (lane >> 4) * 8;
    unsigned short tmp[8];
#pragma unroll
    for (int j = 0; j < 8; ++j) {
        const int k = kbase + j;
        const float v = (k < (H_ + HINT_)) ? W1[(size_t)k * MLPH_ + n] : 0.0f;
        tmp[j] = f2b(v);
    }
    *(uint4*)(W1B + (((size_t)nt * KT_ + kt) * 64 + lane) * 8) = *(const uint4*)tmp;
}

__global__ __launch_bounds__(512, 6) void wbh_kernel(
    const float* __restrict__ hidden,   // (B,S,H) fp32
    const int*   __restrict__ amask,    // (B,S) int32
    const float* __restrict__ hintf,    // (B,S,HINT) fp32
    const float* __restrict__ b1,       // (64)
    const float* __restrict__ W2,       // (64)
    const float* __restrict__ b2,       // (1)
    const unsigned short* __restrict__ W1B, // packed bf16 W1 fragments
    float* __restrict__ out)            // [0:4096) logits, [4096:8192) mask
{
    // 8 real window rows only; MFMA lanes with m>=8 alias row m&7 (dup D rows
    // are never read). LDS total ~37.4 KB.
    __shared__ unsigned short pooledLds[WPB_ * LDK_];   // 34,944 B
    __shared__ float amLds[ROWS_];
    __shared__ float rinvLds[WPB_];
    __shared__ float partLds[WPB_ * PLD_];

    const int tid = threadIdx.x;
    const int bid = blockIdx.x;                    // 512 blocks
    // XCD-locality swizzle: consecutive chunks land on the same XCD (halo L2 reuse)
    const int gid   = (bid & 7) * 64 + (bid >> 3);
    const int b     = gid >> 6;
    const int chunk = gid & 63;
    const int w0    = chunk * WPB_;
    const int s0    = chunk * (WPB_ * STRIDE_);

    // ---- Phase 0: zero k-pad cols (2052..2175) of the 8 rows; stage mask ----
    if (tid < 8 * 62) {                            // 62 uints x 8 rows
        const int row = tid / 62, cc = tid % 62;
        *(unsigned*)&pooledLds[row * LDK_ + 2052 + cc * 2] = 0u;
    }
    if (tid < ROWS_) {
        const int p = s0 + tid;
        amLds[tid] = (p < S_) ? (float)amask[b * S_ + p] : 0.0f;
    }
    __syncthreads();

    // ---- Phase 1a: denoms + window_mask output ----
    if (tid < WPB_) {
        float s = 0.f;
#pragma unroll
        for (int k = 0; k < WS_; ++k) s += amLds[tid * STRIDE_ + k];
        rinvLds[tid] = 1.0f / fmaxf(s, 1.0f);
        out[(size_t)(B_ * NW_) + (size_t)b * NW_ + w0 + tid] = (s > 0.f) ? 1.0f : 0.0f;
    }
    __syncthreads();

    // ---- Phase 1b: BRANCH-FREE masked pooling, rolling 2-group window ----
    // Weight am is exactly 0.0/1.0: select address (masked row vs dummy row 0,
    // L1-resident) and FMA by am. All 8 loads of a group are unconditional and
    // independent -> issued back-to-back, fine-grained vmcnt drain, ~8 KB in
    // flight per wave instead of 1 KB (the round-2/3 serialization killer).
    const int c0 = tid * 4;
    const float* rowBase = hidden + ((size_t)b * S_ + s0) * H_ + c0;

    floatx4 prev = (floatx4){0.f, 0.f, 0.f, 0.f};
#pragma unroll
    for (int g = 0; g <= WPB_; ++g) {
        float am[STRIDE_];
        const float* ptr[STRIDE_];
#pragma unroll
        for (int k = 0; k < STRIDE_; ++k) {
            const int rr = g * STRIDE_ + k;
            am[k]  = amLds[rr];
            ptr[k] = (am[k] != 0.0f) ? (rowBase + (size_t)rr * H_) : rowBase;
        }
        floatx4 v[STRIDE_];
#pragma unroll
        for (int k = 0; k < STRIDE_; ++k) v[k] = *(const floatx4*)ptr[k];

        floatx4 cur = (floatx4){0.f, 0.f, 0.f, 0.f};
#pragma unroll
        for (int k = 0; k < STRIDE_; ++k) {
            cur.x = fmaf(am[k], v[k].x, cur.x);
            cur.y = fmaf(am[k], v[k].y, cur.y);
            cur.z = fmaf(am[k], v[k].z, cur.z);
            cur.w = fmaf(am[k], v[k].w, cur.w);
        }
        if (g >= 1) {                              // finalize window w = g-1
            const int w = g - 1;
            const floatx4 s = prev + cur;
            const float r = rinvLds[w];
            unsigned short q[4];
            q[0] = f2b(s.x * r); q[1] = f2b(s.y * r);
            q[2] = f2b(s.z * r); q[3] = f2b(s.w * r);
            *(uint2*)(&pooledLds[w * LDK_ + c0]) = *(const uint2*)q;
        }
        prev = cur;
    }

    if (tid < WPB_ * HINT_) {                      // hint pooling: 32 threads
        const int w = tid >> 2, hc = tid & 3;
        float s = 0.f;
#pragma unroll
        for (int k = 0; k < WS_; ++k) {
            const int rr = w * STRIDE_ + k;
            const float amv = amLds[rr];
            float hv = 0.f;
            if (amv != 0.0f)                       // tiny, 32 threads only
                hv = hintf[((size_t)b * S_ + (s0 + rr)) * HINT_ + hc];
            s += amv * hv;
        }
        pooledLds[w * LDK_ + H_ + hc] = f2b(s * rinvLds[w]);
    }
    __syncthreads();

    // ---- Phase 2: MFMA (16x2176)@(2176x64); waves 0..3 = n-tiles, full K ----
    const int wid  = tid >> 6;
    const int lane = tid & 63;
    if (wid < NT_) {
        floatx4 dacc = (floatx4){0.f, 0.f, 0.f, 0.f};
        // A-frag: lane holds A[m=lane&15][k=kt*32+(lane>>4)*8+j]; row aliased m&7
        const unsigned short* aBase = pooledLds + (lane & 7) * LDK_ + (lane >> 4) * 8;
        const unsigned short* bBase = W1B + ((size_t)wid * KT_ * 64 + lane) * 8;
#pragma unroll 4
        for (int kt = 0; kt < KT_; ++kt) {
            const shortx8 af = *(const shortx8*)(aBase + kt * 32);
            const shortx8 bf = *(const shortx8*)(bBase + (size_t)kt * 64 * 8);
            dacc = __builtin_amdgcn_mfma_f32_16x16x32_bf16(af, bf, dacc, 0, 0, 0);
        }
        // D: lane reg r holds D[row=(lane>>4)*4+r][col=lane&15]; rows >=8 dups
        if (lane < 32) {
            const int m0 = (lane >> 4) * 4;
            const int j  = wid * 16 + (lane & 15);
#pragma unroll
            for (int r = 0; r < 4; ++r)
                partLds[(m0 + r) * PLD_ + j] = dacc[r];
        }
    }
    __syncthreads();

    // ---- Phase 3: wave m = window m; lane j; gelu + W2 + shuffle reduce ----
    {
        const int m = tid >> 6;
        const int j = tid & 63;
        const float a = partLds[m * PLD_ + j] + b1[j];
        float g = 0.5f * a * (1.0f + erff(a * 0.70710678118654752f)) * W2[j];
#pragma unroll
        for (int off = 32; off > 0; off >>= 1) g += __shfl_down(g, off, 64);
        if (j == 0) out[(size_t)b * NW_ + w0 + m] = g + b2[0];
    }
}

extern "C" void kernel_launch(void* const* d_in, const int* in_sizes, int n_in,
                              void* d_out, int out_size, void* d_ws, size_t ws_size,
                              hipStream_t stream) {
    const float* hidden = (const float*)d_in[0];
    const int*   amask  = (const int*)d_in[1];
    const float* hintf  = (const float*)d_in[2];
    const float* W1     = (const float*)d_in[3];
    const float* b1     = (const float*)d_in[4];
    const float* W2     = (const float*)d_in[5];
    const float* b2     = (const float*)d_in[6];
    float* out          = (float*)d_out;

    unsigned short* W1B = (unsigned short*)d_ws;   // NT_*KT_*64*8*2 = 278,528 B

    // d_ws is re-poisoned before every timed launch -> rebuild packed W1 every call
    prep_w1<<<NT_ * KT_, 64, 0, stream>>>(W1, W1B);
    wbh_kernel<<<B_ * (NW_ / WPB_), 512, 0, stream>>>(
        hidden, amask, hintf, b1, W2, b2, W1B, out);
}